// Round 1
// baseline (415.064 us; speedup 1.0000x reference)
//
#include <hip/hip_runtime.h>

#define CUTOFF_F 5.2f

// One block per (batch b, row i). Threads stride over j in (i, N).
// Output layout (all float32 views):
//   [0,      P)    : idx0 (as float, -1 if invalid)
//   [P,     2P)    : idx1 (as float, -1 if invalid)
//   [2P,    3P)    : dist (0 if invalid)
//   [3P,    6P)    : diff[P][3] (0 if invalid)
__global__ __launch_bounds__(256) void AllPairs_kernel(
    const int* __restrict__ species,
    const float* __restrict__ coords,
    float* __restrict__ out,
    int N, int Psingle, int Ptotal)
{
    const int i = blockIdx.x;       // 0 .. N-2
    const int b = blockIdx.y;       // 0 .. B-1

    // row start within this batch's triangular pair list
    const int rowStart = i * (N - 1) - (i * (i - 1)) / 2;
    const int baseAtom = b * N;

    // broadcast atom i data (L1-resident)
    const float cix = coords[(baseAtom + i) * 3 + 0];
    const float ciy = coords[(baseAtom + i) * 3 + 1];
    const float ciz = coords[(baseAtom + i) * 3 + 2];
    const bool dummy_i = (species[baseAtom + i] == -1);

    float* __restrict__ ind0 = out;
    float* __restrict__ ind1 = out + Ptotal;
    float* __restrict__ dstp = out + 2 * Ptotal;
    float* __restrict__ dfp  = out + 3 * Ptotal;

    const int gBase = b * Psingle + rowStart - (i + 1); // so g = gBase + j

    for (int j = i + 1 + (int)threadIdx.x; j < N; j += (int)blockDim.x) {
        const float dx = cix - coords[(baseAtom + j) * 3 + 0];
        const float dy = ciy - coords[(baseAtom + j) * 3 + 1];
        const float dz = ciz - coords[(baseAtom + j) * 3 + 2];
        const float d  = sqrtf(dx * dx + dy * dy + dz * dz);

        const bool dummy_j = (species[baseAtom + j] == -1);
        const bool valid = (!dummy_i) && (!dummy_j) && (d <= CUTOFF_F);

        const int g = gBase + j;

        ind0[g] = valid ? (float)(baseAtom + i) : -1.0f;
        ind1[g] = valid ? (float)(baseAtom + j) : -1.0f;
        dstp[g] = valid ? d : 0.0f;

        const float ox = valid ? dx : 0.0f;
        const float oy = valid ? dy : 0.0f;
        const float oz = valid ? dz : 0.0f;
        dfp[3 * g + 0] = ox;
        dfp[3 * g + 1] = oy;
        dfp[3 * g + 2] = oz;
    }
}

extern "C" void kernel_launch(void* const* d_in, const int* in_sizes, int n_in,
                              void* d_out, int out_size, void* d_ws, size_t ws_size,
                              hipStream_t stream) {
    const int* species = (const int*)d_in[0];   // [B, N] int32
    const float* coords = (const float*)d_in[1]; // [B, N, 3] float32

    const int S = in_sizes[0];                  // B*N
    // out_size = 6 * B * N*(N-1)/2 = 3 * S * (N-1)  =>  N = out_size/(3*S) + 1
    const int N = out_size / (3 * S) + 1;
    const int B = S / N;
    const int Psingle = (N * (N - 1)) / 2;
    const int Ptotal = B * Psingle;

    dim3 grid(N - 1, B, 1);
    dim3 block(256, 1, 1);
    AllPairs_kernel<<<grid, block, 0, stream>>>(species, coords, (float*)d_out,
                                                N, Psingle, Ptotal);
}

// Round 3
// 401.614 us; speedup vs baseline: 1.0335x; 1.0335x over previous
//
#include <hip/hip_runtime.h>

#define CUTOFF_F 5.2f

typedef float f4 __attribute__((ext_vector_type(4)));

// Each thread handles 4 consecutive pairs of one batch's triangular pair list.
// Output layout (float32):
//   [0,   P) idx0 (-1 if invalid)   [P,  2P) idx1
//   [2P, 3P) dist (0 if invalid)    [3P, 6P) diff[P][3]
__global__ __launch_bounds__(256) void AllPairs_kernel(
    const int* __restrict__ species,
    const float* __restrict__ coords,
    float* __restrict__ out,
    int N, int Psingle, int Ptotal)
{
    const int b  = blockIdx.y;
    const int p0 = (blockIdx.x * 256 + (int)threadIdx.x) * 4;
    if (p0 >= Psingle) return;

    const int M = 2 * N - 1;   // rowStart(i) = i*(M-i)/2

    // fp32 triangular inversion + exact integer correction
    const float s = sqrtf((float)(M * M - 8 * p0));   // M*M < 2^24: exact
    int i = (int)(((float)M - s) * 0.5f);
    if (i < 0) i = 0;
    if (i > N - 2) i = N - 2;
    while (i > 0 && p0 < (i * (M - i)) / 2) --i;
    while (p0 >= ((i + 1) * (M - i - 1)) / 2) ++i;

    int rs = (i * (M - i)) / 2;     // rowStart(i)
    int re = rs + (N - 1 - i);      // rowStart(i+1)

    const int baseAtom = b * N;

    float vi0[4], vi1[4], vd[4], vdf[12];

#pragma unroll
    for (int k = 0; k < 4; ++k) {
        const int p = p0 + k;
        while (p >= re) { ++i; rs = re; re += (N - 1 - i); }
        const int j  = p - rs + i + 1;
        const int ai = baseAtom + i;
        const int aj = baseAtom + j;

        const float dx = coords[ai * 3 + 0] - coords[aj * 3 + 0];
        const float dy = coords[ai * 3 + 1] - coords[aj * 3 + 1];
        const float dz = coords[ai * 3 + 2] - coords[aj * 3 + 2];
        const float d  = sqrtf(dx * dx + dy * dy + dz * dz);

        const bool valid = (species[ai] != -1) && (species[aj] != -1) &&
                           (d <= CUTOFF_F);

        vi0[k] = valid ? (float)ai : -1.0f;
        vi1[k] = valid ? (float)aj : -1.0f;
        vd[k]  = valid ? d : 0.0f;
        vdf[3 * k + 0] = valid ? dx : 0.0f;
        vdf[3 * k + 1] = valid ? dy : 0.0f;
        vdf[3 * k + 2] = valid ? dz : 0.0f;
    }

    const int g0 = b * Psingle + p0;   // multiple of 4 -> 16B aligned

    float* __restrict__ ind0 = out;
    float* __restrict__ ind1 = out + Ptotal;
    float* __restrict__ dstp = out + 2 * (size_t)Ptotal;
    float* __restrict__ dfp  = out + 3 * (size_t)Ptotal;

    *(f4*)(ind0 + g0) = (f4){vi0[0], vi0[1], vi0[2], vi0[3]};
    *(f4*)(ind1 + g0) = (f4){vi1[0], vi1[1], vi1[2], vi1[3]};
    *(f4*)(dstp + g0) = (f4){vd[0],  vd[1],  vd[2],  vd[3]};

    f4* __restrict__ pdf = (f4*)(dfp + 3 * (size_t)g0);  // 48B/thread, 16B aligned
    pdf[0] = (f4){vdf[0], vdf[1], vdf[2],  vdf[3]};
    pdf[1] = (f4){vdf[4], vdf[5], vdf[6],  vdf[7]};
    pdf[2] = (f4){vdf[8], vdf[9], vdf[10], vdf[11]};
}

extern "C" void kernel_launch(void* const* d_in, const int* in_sizes, int n_in,
                              void* d_out, int out_size, void* d_ws, size_t ws_size,
                              hipStream_t stream) {
    const int* species  = (const int*)d_in[0];   // [B, N] int32
    const float* coords = (const float*)d_in[1]; // [B, N, 3] float32

    const int S = in_sizes[0];                   // B*N
    // out_size = 3 * S * (N-1)  =>  N = out_size/(3*S) + 1
    const int N = out_size / (3 * S) + 1;
    const int B = S / N;
    const int Psingle = (N * (N - 1)) / 2;
    const int Ptotal  = B * Psingle;

    const int chunks = (Psingle + 3) / 4;
    dim3 grid((chunks + 255) / 256, B, 1);
    dim3 block(256, 1, 1);
    AllPairs_kernel<<<grid, block, 0, stream>>>(species, coords, (float*)d_out,
                                                N, Psingle, Ptotal);
}